// Round 8
// baseline (282.045 us; speedup 1.0000x reference)
//
#include <hip/hip_runtime.h>

// GMMNet: B=4,S=8,C=3,H=W=384,K=5. Pointwise per pixel; scan over S carries
// per-pixel state (pi[5], mu[15], rinv[5]=1/sigma) in registers.
//
// Round 16: NEURON-PAIR PACKING (1 px/thread). ISA-level diagnosis of the
// 6-round register impasse: v_pk_fma_f32 (VOP3P) sources are 64-bit PAIRS.
// Pixel-pair packing needs every WEIGHT splatted {w,w} into a VGPR pair
// (345 in mu-L1 alone) -> the 224-reg pressure + mov overhead. Neuron
// packing inverts it: weights staged as ADJACENT PAIRS {W[j,i],W[j+1,i]}
// in d_ws, s_load'd into SGPR pairs (legal single-scalar VOP3P operand,
// zero VGPRs); inputs need 1 splat per input element (23/layer) not per
// weight (345/layer). State halves to ~36 regs; peak ~80-100 -> allocator
// fits 128 (it complies when pressure fits: R11). Pad halves (K=5, O=15
// odd) cost ~15-20% extra pk ops; pads are never READ (softmax max/sum
// over real elements only; all input extractions index real elements),
// so no masking. mu-L2 pairs outputs (j,j+3) so muN lands directly in the
// {k,k+1}-per-c layout density consumes.
// Predict: VGPR<=36 units, occ>=50%, busy 88-96%, dispatch ~95-115us.
// Tripwires: absmax fail => pairing index bug (check OMW2/P9); low VGPR
// but busy<80% => weight s_load latency -> software prefetch next.
//
// Retained: ONE contiguous d_ws weight buffer (re-paired by staging
// kernel), opaque per-step scalar offset (blocks cross-step hoisting of
// weight values), xn prefetch.

namespace {

constexpr int Cc = 3;
constexpr int Bb = 4;
constexpr int Ss = 8;
constexpr int HWc = 384 * 384;
constexpr int BLOCK = 256;

// Pair-layout weight offsets (floats; all pair arrays at even offsets).
// Pairings: P3=(0,1),(2,3),(4,-)  P8=(0,1),(2,3),..,(14,-)
//           P9=(0,3),(1,4),(2,5),(6,9),(7,10),(8,11),(12,-),(13,-),(14,-)
constexpr int OPB1 = 0;     // pi_b1  P3: 3 pairs   = 6
constexpr int OPW1 = 6;     // pi_w1  I=10,NP=3     = 60
constexpr int OPB2 = 66;    // pi_b2  P3            = 6
constexpr int OPW2 = 72;    // pi_w2  I=5,NP=3      = 30
constexpr int OMB1 = 102;   // mu_b1  P8: 8 pairs   = 16
constexpr int OMW1 = 118;   // mu_w1  I=23,NP=8     = 368
constexpr int OMB2 = 486;   // mu_b2  P9: 9 pairs   = 18
constexpr int OMW2 = 504;   // mu_w2  I=15,NP=9     = 270
constexpr int OSB1 = 774;   // sg_b1  P3            = 6
constexpr int OSW1 = 780;   // sg_w1  I=23,NP=3     = 138
constexpr int OSB2 = 918;   // sg_b2  P3            = 6
constexpr int OSW2 = 924;   // sg_w2  I=5,NP=3      = 30
constexpr int OGB1 = 954;   // ga_b1  P3            = 6
constexpr int OGW1 = 960;   // ga_w1  I=5,NP=3      = 30
constexpr int OGW2 = 990;   // ga_w2  scalar        = 5
constexpr int OGB2 = 995;   // ga_b2  scalar        = 1
constexpr int WTOT = 996;   // 3984 B

// v2f (pair) index bases = float offset / 2.
constexpr int HPB1 = OPB1 / 2;
constexpr int HPW1 = OPW1 / 2;
constexpr int HPB2 = OPB2 / 2;
constexpr int HPW2 = OPW2 / 2;
constexpr int HMB1 = OMB1 / 2;
constexpr int HMW1 = OMW1 / 2;
constexpr int HMB2 = OMB2 / 2;
constexpr int HMW2 = OMW2 / 2;
constexpr int HSB1 = OSB1 / 2;
constexpr int HSW1 = OSW1 / 2;
constexpr int HSB2 = OSB2 / 2;
constexpr int HSW2 = OSW2 / 2;
constexpr int HGB1 = OGB1 / 2;
constexpr int HGW1 = OGW1 / 2;

typedef float v2f __attribute__((ext_vector_type(2)));

__device__ __forceinline__ float rcpf(float x) { return __builtin_amdgcn_rcpf(x); }
__device__ __forceinline__ float ex2(float x) { return __builtin_amdgcn_exp2f(x); }

__device__ __forceinline__ v2f vsplat(float w) { v2f r = {w, w}; return r; }
__device__ __forceinline__ v2f vfma(v2f a, v2f b, v2f c) { return __builtin_elementwise_fma(a, b, c); }
__device__ __forceinline__ v2f vexp2(v2f v) { v2f r; r.x = ex2(v.x); r.y = ex2(v.y); return r; }
__device__ __forceinline__ v2f vrcp(v2f v) { v2f r; r.x = rcpf(v.x); r.y = rcpf(v.y); return r; }
__device__ __forceinline__ v2f vmax(v2f a, v2f b) { return __builtin_elementwise_max(a, b); }
__device__ __forceinline__ v2f vrelu(v2f a) { return vmax(a, vsplat(0.0f)); }
constexpr float LOG2E = 1.4426950408889634f;
__device__ __forceinline__ v2f vsigm(v2f a) { return vrcp(vsplat(1.0f) + vexp2(vsplat(-LOG2E) * a)); }
// Extract half (sel must be compile-time constant after unrolling).
__device__ __forceinline__ float hx(v2f v, int sel) { return sel ? v.y : v.x; }

__global__ __launch_bounds__(256) void stage_ws_kernel(
    const float* __restrict__ pw1, const float* __restrict__ pb1,
    const float* __restrict__ pw2, const float* __restrict__ pb2,
    const float* __restrict__ mw1, const float* __restrict__ mb1,
    const float* __restrict__ mw2, const float* __restrict__ mb2,
    const float* __restrict__ sw1, const float* __restrict__ sb1,
    const float* __restrict__ sw2, const float* __restrict__ sb2,
    const float* __restrict__ gw1, const float* __restrict__ gb1,
    const float* __restrict__ gw2, const float* __restrict__ gb2,
    float* __restrict__ ws)
{
    const int t = threadIdx.x;
    // Re-pair weights: ws pair (i,p) = { w[lo[p]*I+i], hi[p]>=0 ? w[hi[p]*I+i] : 0 }
    auto pairs = [&](const float* w, const float* bsrc, int I, int NP,
                     const int* lo, const int* hi, int wOff, int bOff) {
        for (int idx = t; idx < I * NP; idx += 256) {
            int i = idx / NP, p = idx - (idx / NP) * NP;
            ws[wOff + 2 * idx]     = w[lo[p] * I + i];
            ws[wOff + 2 * idx + 1] = (hi[p] >= 0) ? w[hi[p] * I + i] : 0.0f;
        }
        for (int p = t; p < NP; p += 256) {
            ws[bOff + 2 * p]     = bsrc[lo[p]];
            ws[bOff + 2 * p + 1] = (hi[p] >= 0) ? bsrc[hi[p]] : 0.0f;
        }
    };
    const int lo3[3] = {0, 2, 4},                 hi3[3] = {1, 3, -1};
    const int lo8[8] = {0, 2, 4, 6, 8, 10, 12, 14}, hi8[8] = {1, 3, 5, 7, 9, 11, 13, -1};
    const int lo9[9] = {0, 1, 2, 6, 7, 8, 12, 13, 14}, hi9[9] = {3, 4, 5, 9, 10, 11, -1, -1, -1};
    pairs(pw1, pb1, 10, 3, lo3, hi3, OPW1, OPB1);
    pairs(pw2, pb2,  5, 3, lo3, hi3, OPW2, OPB2);
    pairs(mw1, mb1, 23, 8, lo8, hi8, OMW1, OMB1);
    pairs(mw2, mb2, 15, 9, lo9, hi9, OMW2, OMB2);
    pairs(sw1, sb1, 23, 3, lo3, hi3, OSW1, OSB1);
    pairs(sw2, sb2,  5, 3, lo3, hi3, OSW2, OSB2);
    pairs(gw1, gb1,  5, 3, lo3, hi3, OGW1, OGB1);
    if (t < 5)  ws[OGW2 + t] = gw2[t];
    if (t == 0) ws[OGB2] = gb2[0];
}

__global__ __launch_bounds__(BLOCK, 4)
void gmm_seq_kernel(
    const float* __restrict__ frames,
    const float* __restrict__ mu0,
    const float* __restrict__ Wt,     // pair-staged weights in d_ws
    float* __restrict__ out)
{
    const int t = blockIdx.x * BLOCK + threadIdx.x;    // one thread = 1 pixel
    const int b   = t / HWc;
    const int rem = t - b * HWc;

    const float C0 = 0.06349363593424097f;      // (2*pi)^{-3/2}
    const float NH_L2E = -0.7213475204444817f;  // -0.5 * log2(e)

    // Carried state, packed over k-PAIRS (pad half in [2].y, never read):
    //   piP[kp]          = {pi[2kp],   pi[2kp+1]}
    //   rinvP[kp]        = {rinv[2kp], rinv[2kp+1]}
    //   muP[kp*3+c]      = {mu[(2kp)*3+c], mu[(2kp+1)*3+c]}
    v2f piP[3], muP[9], rinvP[3];
    piP[0] = vsplat(0.2f); piP[1] = vsplat(0.2f); piP[2] = {0.2f, 0.0f};
    rinvP[0] = vsplat(1.0f); rinvP[1] = vsplat(1.0f); rinvP[2] = {1.0f, 0.0f};
    {
        const float* mp = mu0 + (size_t)b * 15 * HWc;
#pragma unroll
        for (int kp = 0; kp < 3; kp++)
#pragma unroll
            for (int c = 0; c < 3; c++) {
                float lo = mp[(size_t)((2 * kp) * 3 + c) * HWc + rem];
                float hi = (kp < 2) ? mp[(size_t)((2 * kp + 1) * 3 + c) * HWc + rem] : 0.0f;
                muP[kp * 3 + c] = {lo, hi};
            }
    }

    const float* fbase = frames + ((size_t)b * Ss * Cc) * HWc;
    float x[Cc];
#pragma unroll
    for (int c = 0; c < Cc; c++) x[c] = fbase[(size_t)c * HWc + rem];

#pragma unroll 1
    for (int s = 0; s < Ss; s++) {
        // Opaque per-iteration SCALAR offset (value 0, unprovable): keeps
        // weight loads loop-variant; addresses wave-uniform (s_load path).
        long woff = 0;
        asm volatile("" : "+s"(woff));
        const float* W = Wt + woff;
        const v2f* W2 = reinterpret_cast<const v2f*>(W);

        // Prefetch next frame (clamped -> branchless).
        const int sn = (s + 1 < Ss) ? s + 1 : s;
        float xn[Cc];
        {
            const float* fp = fbase + ((size_t)sn * Cc) * HWc;
#pragma unroll
            for (int c = 0; c < Cc; c++) xn[c] = fp[(size_t)c * HWc + rem];
        }

        v2f xs[Cc];
#pragma unroll
        for (int c = 0; c < Cc; c++) xs[c] = vsplat(x[c]);

        // ---- density(x; mu, rinv), packed over k-pairs ----
        v2f alpha2[3], rho2[3];
#pragma unroll
        for (int kp = 0; kp < 3; kp++) {
            v2f ri  = rinvP[kp];
            v2f is2 = ri * ri;
            v2f d0 = xs[0] - muP[kp * 3 + 0];
            v2f d1 = xs[1] - muP[kp * 3 + 1];
            v2f d2 = xs[2] - muP[kp * 3 + 2];
            v2f dist = vfma(d0, d0, vfma(d1, d1, d2 * d2));
            v2f coef = vsplat(C0) * is2 * ri;
            v2f dens = coef * vexp2(vsplat(NH_L2E) * dist * is2);
            alpha2[kp] = piP[kp] * dens;
            rho2[kp]   = alpha2[kp] * dens;
        }

        // ---- pi MLP (10 -> 5 -> 5, pairs P3) + softmax over real 5 ----
        {
            v2f hp[3];
#pragma unroll
            for (int p = 0; p < 3; p++) hp[p] = W2[HPB1 + p];
#pragma unroll
            for (int i = 0; i < 5; i++) {
                v2f sv = vsplat(hx(piP[i >> 1], i & 1));
#pragma unroll
                for (int p = 0; p < 3; p++) hp[p] = vfma(W2[HPW1 + i * 3 + p], sv, hp[p]);
            }
#pragma unroll
            for (int i = 0; i < 5; i++) {
                v2f sv = vsplat(hx(alpha2[i >> 1], i & 1));
#pragma unroll
                for (int p = 0; p < 3; p++) hp[p] = vfma(W2[HPW1 + (5 + i) * 3 + p], sv, hp[p]);
            }
#pragma unroll
            for (int p = 0; p < 3; p++) hp[p] = vrelu(hp[p]);

            v2f o2[3];
#pragma unroll
            for (int p = 0; p < 3; p++) o2[p] = W2[HPB2 + p];
#pragma unroll
            for (int i = 0; i < 5; i++) {
                v2f sv = vsplat(hx(hp[i >> 1], i & 1));
#pragma unroll
                for (int p = 0; p < 3; p++) o2[p] = vfma(W2[HPW2 + i * 3 + p], sv, o2[p]);
            }
            // softmax over real 5 only (pad o2[2].y excluded from max & sum)
            float m = fmaxf(fmaxf(fmaxf(o2[0].x, o2[0].y), fmaxf(o2[1].x, o2[1].y)), o2[2].x);
            v2f e0 = vexp2(vsplat(LOG2E) * (o2[0] - vsplat(m)));
            v2f e1 = vexp2(vsplat(LOG2E) * (o2[1] - vsplat(m)));
            v2f e2 = vexp2(vsplat(LOG2E) * (o2[2] - vsplat(m)));
            float sum = e0.x + e0.y + e1.x + e1.y + e2.x;
            float r = rcpf(sum);
            piP[0] = e0 * vsplat(r); piP[1] = e1 * vsplat(r); piP[2] = e2 * vsplat(r);
        }

        // ---- mu MLP (23 -> 15 -> 15): L1 pairs P8, L2 pairs P9 (=density layout) ----
        {
            v2f hm[8];
#pragma unroll
            for (int p = 0; p < 8; p++) hm[p] = W2[HMB1 + p];
#pragma unroll
            for (int c = 0; c < 3; c++) {
#pragma unroll
                for (int p = 0; p < 8; p++) hm[p] = vfma(W2[HMW1 + c * 8 + p], xs[c], hm[p]);
            }
#pragma unroll
            for (int j = 0; j < 15; j++) {
                const int k = j / 3, c = j - 3 * (j / 3);
                v2f sv = vsplat(hx(muP[(k >> 1) * 3 + c], k & 1));
#pragma unroll
                for (int p = 0; p < 8; p++) hm[p] = vfma(W2[HMW1 + (3 + j) * 8 + p], sv, hm[p]);
            }
#pragma unroll
            for (int k = 0; k < 5; k++) {
                v2f sv = vsplat(hx(rho2[k >> 1], k & 1));
#pragma unroll
                for (int p = 0; p < 8; p++) hm[p] = vfma(W2[HMW1 + (18 + k) * 8 + p], sv, hm[p]);
            }
#pragma unroll
            for (int p = 0; p < 8; p++) hm[p] = vrelu(hm[p]);

            v2f am[9];
#pragma unroll
            for (int q = 0; q < 9; q++) am[q] = W2[HMB2 + q];
#pragma unroll
            for (int j = 0; j < 15; j++) {
                v2f sv = vsplat(hx(hm[j >> 1], j & 1));
#pragma unroll
                for (int q = 0; q < 9; q++) am[q] = vfma(W2[HMW2 + j * 9 + q], sv, am[q]);
            }
#pragma unroll
            for (int q = 0; q < 9; q++) muP[q] = vsigm(am[q]);   // mu := mu_new (density layout)
        }

        // ---- sigma MLP (23 -> 5 -> 5): L1 pairs P3, L2 pairs P3 (k-layout) ----
        {
            v2f hs[3];
#pragma unroll
            for (int p = 0; p < 3; p++) hs[p] = W2[HSB1 + p];
#pragma unroll
            for (int c = 0; c < 3; c++) {
#pragma unroll
                for (int p = 0; p < 3; p++) hs[p] = vfma(W2[HSW1 + c * 3 + p], xs[c], hs[p]);
            }
#pragma unroll
            for (int j = 0; j < 15; j++) {
                const int k = j / 3, c = j - 3 * (j / 3);
                v2f sv = vsplat(hx(muP[(k >> 1) * 3 + c], k & 1));   // mu_new
#pragma unroll
                for (int p = 0; p < 3; p++) hs[p] = vfma(W2[HSW1 + (3 + j) * 3 + p], sv, hs[p]);
            }
#pragma unroll
            for (int k = 0; k < 5; k++) {
                v2f sv = vsplat(hx(rho2[k >> 1], k & 1));
#pragma unroll
                for (int p = 0; p < 3; p++) hs[p] = vfma(W2[HSW1 + (18 + k) * 3 + p], sv, hs[p]);
            }
#pragma unroll
            for (int p = 0; p < 3; p++) hs[p] = vrelu(hs[p]);

            v2f as2[3];
#pragma unroll
            for (int p = 0; p < 3; p++) as2[p] = W2[HSB2 + p];
#pragma unroll
            for (int i = 0; i < 5; i++) {
                v2f sv = vsplat(hx(hs[i >> 1], i & 1));
#pragma unroll
                for (int p = 0; p < 3; p++) as2[p] = vfma(W2[HSW2 + i * 3 + p], sv, as2[p]);
            }
#pragma unroll
            for (int p = 0; p < 3; p++)
                rinvP[p] = vexp2(vsplat(-LOG2E) * vrelu(as2[p]));  // rinv := 1/sigma_new
        }

        // ---- dens2(x; mu_new, rinv_new) packed; gamma MLP (5 -> 5 -> 1) ----
        v2f gin[3];
#pragma unroll
        for (int kp = 0; kp < 3; kp++) {
            v2f ri  = rinvP[kp];
            v2f is2 = ri * ri;
            v2f d0 = xs[0] - muP[kp * 3 + 0];
            v2f d1 = xs[1] - muP[kp * 3 + 1];
            v2f d2 = xs[2] - muP[kp * 3 + 2];
            v2f dist = vfma(d0, d0, vfma(d1, d1, d2 * d2));
            v2f coef = vsplat(C0) * is2 * ri;
            gin[kp] = piP[kp] * (coef * vexp2(vsplat(NH_L2E) * dist * is2));
        }
        {
            v2f hg[3];
#pragma unroll
            for (int p = 0; p < 3; p++) hg[p] = W2[HGB1 + p];
#pragma unroll
            for (int i = 0; i < 5; i++) {
                v2f sv = vsplat(hx(gin[i >> 1], i & 1));
#pragma unroll
                for (int p = 0; p < 3; p++) hg[p] = vfma(W2[HGW1 + i * 3 + p], sv, hg[p]);
            }
#pragma unroll
            for (int p = 0; p < 3; p++) hg[p] = vrelu(hg[p]);

            float go = W[OGB2];
#pragma unroll
            for (int i = 0; i < 5; i++) go = fmaf(W[OGW2 + i], hx(hg[i >> 1], i & 1), go);
            out[(size_t)(b * Ss + s) * HWc + rem] = rcpf(1.0f + ex2(-LOG2E * go));
        }

        // ---- advance frame ----
#pragma unroll
        for (int c = 0; c < Cc; c++) x[c] = xn[c];
    }
}

} // namespace

extern "C" void kernel_launch(void* const* d_in, const int* in_sizes, int n_in,
                              void* d_out, int out_size, void* d_ws, size_t ws_size,
                              hipStream_t stream) {
    const float* frames = (const float*)d_in[0];
    const float* mu0    = (const float*)d_in[2];
    const float* pw1 = (const float*)d_in[3];
    const float* pb1 = (const float*)d_in[4];
    const float* pw2 = (const float*)d_in[5];
    const float* pb2 = (const float*)d_in[6];
    const float* mw1 = (const float*)d_in[7];
    const float* mb1 = (const float*)d_in[8];
    const float* mw2 = (const float*)d_in[9];
    const float* mb2 = (const float*)d_in[10];
    const float* sw1 = (const float*)d_in[11];
    const float* sb1 = (const float*)d_in[12];
    const float* sw2 = (const float*)d_in[13];
    const float* sb2 = (const float*)d_in[14];
    const float* gw1 = (const float*)d_in[15];
    const float* gb1 = (const float*)d_in[16];
    const float* gw2 = (const float*)d_in[17];
    const float* gb2 = (const float*)d_in[18];
    float* out = (float*)d_out;
    float* ws  = (float*)d_ws;

    // Stage weights into pair layout in d_ws.
    stage_ws_kernel<<<1, 256, 0, stream>>>(
        pw1, pb1, pw2, pb2, mw1, mb1, mw2, mb2,
        sw1, sb1, sw2, sb2, gw1, gb1, gw2, gb2, ws);

    const int total = Bb * HWc;                      // 589,824 pixels
    const int grid = (total + BLOCK - 1) / BLOCK;    // 2304 blocks of 256

    gmm_seq_kernel<<<grid, BLOCK, 0, stream>>>(frames, mu0, ws, out);
}